// Round 1
// baseline (257.413 us; speedup 1.0000x reference)
//
#include <hip/hip_runtime.h>
#include <math.h>

#define NSLICE 64
#define DVEC   131072      // D/4 = 524288/4 float4 per slice
#define NB     32          // chunks per slice
#define CHUNK4 (DVEC/NB)   // 4096 float4 per block
#define TPB    256

__inline__ __device__ float wave_reduce(float v) {
    #pragma unroll
    for (int off = 32; off > 0; off >>= 1) v += __shfl_down(v, off, 64);
    return v;
}

// Kernel A: norms[i] = dot(q[i],q[i]); adj[i] = dot(q[i],q[i+1]) for i < NSLICE-1
__global__ __launch_bounds__(TPB) void dots_kernel(
        const float* __restrict__ q, float* __restrict__ norms, float* __restrict__ adj) {
    const int i = blockIdx.y;
    const int j = blockIdx.x;
    const bool has_next = (i < NSLICE - 1);
    const float4* qi = (const float4*)q + (size_t)i * DVEC + (size_t)j * CHUNK4;
    const float4* qn = qi + DVEC;   // same chunk of slice i+1

    float self = 0.f, cross = 0.f;
    for (int t = threadIdx.x; t < CHUNK4; t += TPB) {
        float4 a = qi[t];
        self += a.x*a.x + a.y*a.y + a.z*a.z + a.w*a.w;
        if (has_next) {
            float4 b = qn[t];
            cross += a.x*b.x + a.y*b.y + a.z*b.z + a.w*b.w;
        }
    }

    __shared__ float s_s[TPB / 64];
    __shared__ float s_c[TPB / 64];
    float sw = wave_reduce(self);
    float cw = wave_reduce(cross);
    const int lane = threadIdx.x & 63;
    const int wid  = threadIdx.x >> 6;
    if (lane == 0) { s_s[wid] = sw; s_c[wid] = cw; }
    __syncthreads();
    if (threadIdx.x == 0) {
        float st = s_s[0] + s_s[1] + s_s[2] + s_s[3];
        float ct = s_c[0] + s_c[1] + s_c[2] + s_c[3];
        atomicAdd(&norms[i], st);
        if (has_next) atomicAdd(&adj[i], ct);
    }
}

// Kernel B: exact branch-ladder indices + softmax weights. 1 block, 64 threads.
__global__ void weights_kernel(
        const float* __restrict__ e, const float* __restrict__ norms,
        const float* __restrict__ adj, float* __restrict__ w1o, float* __restrict__ w2o,
        int* __restrict__ ao, int* __restrict__ bo) {
    const int i = threadIdx.x;           // 0..63
    const float ei = e[i];
    int k1, k2;
    if (i == 0) {
        const int b0 = (ei >= e[1]) ? 1 : 0;
        k1 = b0; k2 = b0;
    } else if (i == NSLICE - 1) {
        const int bL = (ei >= e[NSLICE - 2]) ? (NSLICE - 2) : (NSLICE - 1);
        k1 = bL; k2 = bL;
    } else {
        const float ep = e[i - 1], en = e[i + 1];
        const bool ge_next = (ei >= en), ge_prev = (ei >= ep);
        const bool le_next = (ei <= en), le_prev = (ei <= ep);
        if      (ge_next && ge_prev) { k1 = i - 1; k2 = i + 1; }  // local max
        else if (le_next && ge_prev) { k1 = i - 1; k2 = i;     }  // rising
        else if (ge_next && le_prev) { k1 = i;     k2 = i + 1; }  // falling
        else                         { k1 = i;     k2 = i;     }
    }
    // dot(q[i], q[k]) for k in {i-1, i, i+1}
    const float di  = norms[i];
    const float dlo = (i > 0) ? adj[i - 1] : 0.f;
    const float dhi = (i < NSLICE - 1) ? adj[i] : 0.f;
    const float s_scale = 1.0f / sqrtf(524288.0f);
    const float s1 = ((k1 < i) ? dlo : (k1 > i) ? dhi : di) * s_scale;
    const float s2 = ((k2 < i) ? dlo : (k2 > i) ? dhi : di) * s_scale;
    const float m  = fmaxf(s1, s2);
    const float e1 = expf(s1 - m), e2 = expf(s2 - m);
    const float inv = 1.0f / (e1 + e2);
    w1o[i] = e1 * inv;
    w2o[i] = e2 * inv;
    ao[i] = k1;
    bo[i] = k2;
}

// Kernel C: out[i] = w1[i]*q[a[i]] + w2[i]*q[b[i]]
__global__ __launch_bounds__(TPB) void combine_kernel(
        const float* __restrict__ q, const float* __restrict__ w1,
        const float* __restrict__ w2, const int* __restrict__ ai,
        const int* __restrict__ bi, float* __restrict__ out) {
    const int i = blockIdx.y;
    const int j = blockIdx.x;
    const float wa = w1[i];
    const float wb = w2[i];
    const int a = ai[i];
    const int b = bi[i];
    const float4* qa = (const float4*)q + (size_t)a * DVEC + (size_t)j * CHUNK4;
    const float4* qb = (const float4*)q + (size_t)b * DVEC + (size_t)j * CHUNK4;
    float4* o = (float4*)out + (size_t)i * DVEC + (size_t)j * CHUNK4;
    for (int t = threadIdx.x; t < CHUNK4; t += TPB) {
        float4 x = qa[t];
        float4 y = qb[t];
        float4 r;
        r.x = wa * x.x + wb * y.x;
        r.y = wa * x.y + wb * y.y;
        r.z = wa * x.z + wb * y.z;
        r.w = wa * x.w + wb * y.w;
        o[t] = r;
    }
}

extern "C" void kernel_launch(void* const* d_in, const int* in_sizes, int n_in,
                              void* d_out, int out_size, void* d_ws, size_t ws_size,
                              hipStream_t stream) {
    const float* c5d = (const float*)d_in[0];
    const float* ent = (const float*)d_in[1];
    float* out = (float*)d_out;

    // workspace layout: norms[64] | adj[64] | w1[64] | w2[64] | a[64] | b[64]
    float* norms = (float*)d_ws;
    float* adj   = norms + NSLICE;
    float* w1    = adj + NSLICE;
    float* w2    = w1 + NSLICE;
    int*   a     = (int*)(w2 + NSLICE);
    int*   b     = a + NSLICE;

    // zero only the accumulators (ws is poisoned with 0xAA before every call)
    hipMemsetAsync(d_ws, 0, 2 * NSLICE * sizeof(float), stream);

    dots_kernel<<<dim3(NB, NSLICE), TPB, 0, stream>>>(c5d, norms, adj);
    weights_kernel<<<1, NSLICE, 0, stream>>>(ent, norms, adj, w1, w2, a, b);
    combine_kernel<<<dim3(NB, NSLICE), TPB, 0, stream>>>(c5d, w1, w2, a, b, out);
}